// Round 4
// baseline (1394.111 us; speedup 1.0000x reference)
//
#include <hip/hip_runtime.h>
#include <math.h>

typedef _Float16 half_t;
typedef half_t half8 __attribute__((ext_vector_type(8)));
typedef half_t half4 __attribute__((ext_vector_type(4)));
typedef float  f32x16 __attribute__((ext_vector_type(16)));
typedef double dbl2  __attribute__((ext_vector_type(2)));

// Problem constants
#define BB 4
#define HH 512
#define WW 512
#define IMGPIX (HH*WW)        // 262144
#define KSEL 512
#define NPROP (BB*KSEL)       // 2048
#define CUP 64
#define NMS_THR 0.2f

// Workspace layout (bytes)
#define OFF_S32    0                      // double[4096] = 32768
#define OFF_SUM    32768                  // double
#define OFF_CNT    32776                  // ull
#define OFF_CCNT   32784                  // u32[4]
#define ZERO_BASE  32768
#define ZERO_LEN   32                     // sum, cnt, ccnt
#define OFF_BITMAP 295040                 // u64[16384] = 131072
#define OFF_CAND   426112                 // u64[4][262144] = 8 MB -> 8814720
#define OFF_SEL    8814720                // (unused now, kept for layout stability)
#define OFF_PROPS  8831104                // int[4096]
#define OFF_W1     8847488                // 294912
#define OFF_W2     9142400                // 1179648
#define OFF_W3     10322048               // 1179648 -> 11501696 total

#define CANDCAP (1u<<18)                  // 262144 per image (worst case = all px)

#define LRELU_F(x) ((x) > 0.0f ? (x) : 0.1f*(x))

// ---------------------------------------------------------------------------
// Stage 1 (+fused weight repack): blocks 0..511 = patch MLP, rest = repack
// Repack: qw[oc][ic][3][3] f32 -> [tap][ks(ic/16)][oc][16] f16
// Output-linear thread mapping: coalesced half4 stores (was 2B scatter).
// ---------------------------------------------------------------------------
__global__ __launch_bounds__(256) void repatch_k(
    const float* __restrict__ fdown,
    const float* __restrict__ pw1, const float* __restrict__ pb1,
    const float* __restrict__ pw2, const float* __restrict__ pb2,
    const float* __restrict__ pw3, const float* __restrict__ pb3,
    const float* __restrict__ pfcw, const float* __restrict__ pfcb,
    double* __restrict__ s32,
    const float* __restrict__ qw1, const float* __restrict__ qw2,
    const float* __restrict__ qw3,
    half_t* __restrict__ W1, half_t* __restrict__ W2, half_t* __restrict__ W3)
{
  if (blockIdx.x >= 512) {
    const int tot1q = (256*64*9*16/16)/4;      // 36864 quads for W1
    const int tot2q = (256*256*9*16/16)/4;     // 147456 quads for W2/W3
    int g = (blockIdx.x - 512)*256 + threadIdx.x;
    const float* src; half_t* dst; int IC, KS, q;
    if (g < tot1q)               { src = qw1; dst = W1; IC = 64;  KS = 4;  q = g; }
    else if (g < tot1q + tot2q)  { src = qw2; dst = W2; IC = 256; KS = 16; q = g - tot1q; }
    else if (g < tot1q + 2*tot2q){ src = qw3; dst = W3; IC = 256; KS = 16; q = g - tot1q - tot2q; }
    else return;
    int o4  = q*4;                 // output half index (linear)
    int kin = o4 & 15;
    int t   = o4 >> 4;
    int oc  = t & 255;
    int r   = t >> 8;
    int ks  = r % KS, tap = r / KS;
    half4 h;
#pragma unroll
    for (int j = 0; j < 4; ++j) {
      int ic = ks*16 + kin + j;
      h[j] = (half_t)src[(oc*IC + ic)*9 + tap];
    }
    *(half4*)(dst + o4) = h;
    return;
  }
  __shared__ __align__(16) double xb[8][256];
  const int t = threadIdx.x;
  const int base_px = blockIdx.x * 8;
#pragma unroll
  for (int p = 0; p < 8; ++p) {
    int px = base_px + p;
    int b = px >> 10, rem = px & 1023;
    xb[p][t] = (double)fdown[(size_t)(b*256 + t)*1024 + rem];
  }
  __syncthreads();
  const float* Ws[3] = {pw1, pw2, pw3};
  const float* Bs[3] = {pb1, pb2, pb3};
  for (int L = 0; L < 3; ++L) {
    double acc[8];
    double bias = (double)Bs[L][t];
#pragma unroll
    for (int p = 0; p < 8; ++p) acc[p] = bias;
    const float* wrow = Ws[L] + t*256;
    for (int c = 0; c < 256; c += 2) {
      double w0 = (double)wrow[c], w1 = (double)wrow[c+1];
#pragma unroll
      for (int p = 0; p < 8; ++p) {
        dbl2 xv = *(const dbl2*)&xb[p][c];
        acc[p] += w0 * xv.x;
        acc[p] += w1 * xv.y;
      }
    }
    __syncthreads();
#pragma unroll
    for (int p = 0; p < 8; ++p)
      xb[p][t] = acc[p] > 0.0 ? acc[p] : 0.1*acc[p];
    __syncthreads();
  }
  if (t < 8) {
    double l0 = (double)pfcb[0], l1 = (double)pfcb[1];
    for (int c = 0; c < 256; ++c) {
      double xv = xb[t][c];
      l0 += (double)pfcw[c]       * xv;
      l1 += (double)pfcw[256 + c] * xv;
    }
    double m  = fmax(l0, l1);
    double e0 = exp(l0 - m), e1 = exp(l1 - m);
    s32[base_px + t] = e1 / (e0 + e1);
  }
}

// Bilinear upsample 32->512 (align_corners=False), matches jax.image.resize.
__device__ __forceinline__ double upsample_ps(const double* __restrict__ s32,
                                              int b, int oy, int ox)
{
  double sy = (oy + 0.5)*0.0625 - 0.5;
  double sx = (ox + 0.5)*0.0625 - 0.5;
  double fy = floor(sy), fx = floor(sx);
  double wy = sy - fy,   wx = sx - fx;
  int y0 = (int)fy, x0 = (int)fx;
  int y0i = min(max(y0,   0), 31), y1i = min(max(y0+1, 0), 31);
  int x0i = min(max(x0,   0), 31), x1i = min(max(x0+1, 0), 31);
  const double* s = s32 + b*1024;
  double v00 = s[y0i*32+x0i], v01 = s[y0i*32+x1i];
  double v10 = s[y1i*32+x0i], v11 = s[y1i*32+x1i];
  return v00*(1.0-wy)*(1.0-wx) + v01*(1.0-wy)*wx
       + v10*wy*(1.0-wx)       + v11*wy*wx;
}

// ---------------------------------------------------------------------------
// Stage 2a: global bad-pixel sum/count (f64) + bad bitmap (ballot-packed)
// ---------------------------------------------------------------------------
__global__ __launch_bounds__(256) void mean_k(
    const float* __restrict__ xhat, const double* __restrict__ s32,
    double* __restrict__ sum, unsigned long long* __restrict__ cnt,
    unsigned long long* __restrict__ bitmap)
{
  int id = blockIdx.x*256 + threadIdx.x;
  int b = id >> 18, rem = id & (IMGPIX-1);
  int oy = rem >> 9, ox = rem & 511;
  double ps = upsample_ps(s32, b, oy, ox);
  bool bad = ps < 0.5;
  int lane = threadIdx.x & 63;
  unsigned long long bb = __ballot(bad);
  if (lane == 0) bitmap[id >> 6] = bb;
  double v = bad ? (double)xhat[id] : 0.0;
  int    c = bad ? 1 : 0;
  for (int off = 32; off; off >>= 1) {
    v += __shfl_down(v, off);
    c += __shfl_down(c, off);
  }
  __shared__ double sv[4];
  __shared__ int    sc[4];
  int w = threadIdx.x >> 6;
  if (lane == 0) { sv[w] = v; sc[w] = c; }
  __syncthreads();
  if (threadIdx.x == 0) {
    atomicAdd(sum, sv[0]+sv[1]+sv[2]+sv[3]);
    atomicAdd(cnt, (unsigned long long)(sc[0]+sc[1]+sc[2]+sc[3]));
  }
}

// ---------------------------------------------------------------------------
// Stage 2b: belief map + 7x7 NMS -> COMPACT candidate append (ballot-agg).
// Filler rule: every row-0 pixel (rem<512) is appended even if not a peak;
// those 512 keys dominate every non-appended key (inv >= IMGPIX-512), so the
// top-512 of the compact list == top-512 of all IMGPIX keys, provably.
// ---------------------------------------------------------------------------
__global__ __launch_bounds__(512) void keyfuse_k(
    const float* __restrict__ xhat, const unsigned long long* __restrict__ bitmap,
    const double* __restrict__ sum, const unsigned long long* __restrict__ cnt,
    unsigned long long* __restrict__ candbuf, unsigned int* __restrict__ ccnt)
{
  __shared__ float rowm[14][512];
  __shared__ float bmv[8][512];
  __shared__ float rt[512];
  const int tid = threadIdx.x;
  const int img = blockIdx.x >> 6;
  const int rb  = (blockIdx.x & 63) * 8;

  unsigned long long n = *cnt; if (n < 1) n = 1;
  const float mean = (float)(*sum / (double)n);
  const int ibase = img * IMGPIX;

  for (int r = 0; r < 14; ++r) {
    int y = rb - 3 + r;
    float v = -INFINITY;
    if (y >= 0 && y < 512) {
      int id = ibase + (y << 9) + tid;
      bool bad = (bitmap[id >> 6] >> (id & 63)) & 1ull;
      v = bad ? mean : xhat[id];
    }
    int cr = y - rb;
    if (cr >= 0 && cr < 8) bmv[cr][tid] = v;
    rt[tid] = v;
    __syncthreads();
    int lo = max(tid-3, 0), hi = min(tid+3, 511);
    float m = rt[lo];
    for (int xx = lo+1; xx <= hi; ++xx) m = fmaxf(m, rt[xx]);
    rowm[r][tid] = m;
    __syncthreads();
  }

  const int lane = tid & 63;
  unsigned long long* cb = candbuf + ((size_t)img << 18);
  for (int yy = 0; yy < 8; ++yy) {
    float mp = rowm[yy][tid];
#pragma unroll
    for (int d = 1; d < 7; ++d) mp = fmaxf(mp, rowm[yy + d][tid]);
    float v = bmv[yy][tid];
    bool cand = (v == mp) && (v > NMS_THR);
    int rem = ((rb + yy) << 9) + tid;
    unsigned int inv = (unsigned int)((IMGPIX-1) - rem);
    unsigned long long key = cand
        ? ((((unsigned long long)__float_as_uint(v)) << 18) | inv)
        : (unsigned long long)inv;
    bool keep = cand | (rem < 512);
    unsigned long long m = __ballot(keep);
    int c = __popcll(m);
    if (c) {
      int leader = __ffsll((long long)m) - 1;
      unsigned base = 0;
      if (lane == leader) base = atomicAdd(&ccnt[img], (unsigned)c);
      base = __shfl(base, leader);
      if (keep) {
        unsigned rk = (unsigned)__popcll(m & ((1ull << lane) - 1ull));
        cb[base + rk] = key;
      }
    }
  }
}

// ---------------------------------------------------------------------------
// Fused select: 4-pass in-LDS radix cut over the compact candidate list,
// then collect >= cutkey + bitonic sort 512 (desc) + outputs.
// Replaces 3x hist_k + 4x scan_k + collect_k + sortout_k (8 launches).
// One block per image. Ballot-dedup histogram (bad-blob cands share one bin).
// ---------------------------------------------------------------------------
__global__ __launch_bounds__(512) void select_k(
    const unsigned long long* __restrict__ candbuf,
    const unsigned int* __restrict__ ccnt,
    float* __restrict__ out, int* __restrict__ props)
{
  __shared__ unsigned int lh[4096];
  __shared__ unsigned int lsA[512], lsB[512];
  __shared__ unsigned long long sel[512];
  __shared__ unsigned long long pfx_s;
  __shared__ unsigned int R_s, cnt_s;

  const int b = blockIdx.x, tid = threadIdx.x;
  const int lane = tid & 63;
  const unsigned long long* cb = candbuf + ((size_t)b << 18);
  unsigned int n = ccnt[b]; if (n > CANDCAP) n = CANDCAP;

  if (tid == 0) { pfx_s = 0ull; R_s = (unsigned)KSEL; cnt_s = 0u; }
  __syncthreads();

  for (int pass = 0; pass < 4; ++pass) {
    const int shift = 36 - 12*pass;
    const unsigned long long pfxv = pfx_s;
    const unsigned int Rv = R_s;
    for (int i = tid; i < 4096; i += 512) lh[i] = 0;
    __syncthreads();

    for (unsigned i0 = 0; i0 < n; i0 += 512) {
      unsigned i = i0 + tid;
      unsigned long long k = (i < n) ? cb[i] : 0ull;
      bool pred = (i < n) && (pass == 0 || (k >> (shift + 12)) == pfxv);
      int bin = (int)((unsigned)(k >> shift) & 4095u);
      unsigned long long active = __ballot(pred);
      while (active) {
        int src = __ffsll((long long)active) - 1;
        int bsel = __shfl(bin, src);
        unsigned long long match = __ballot(bin == bsel) & active;
        if (lane == src) atomicAdd(&lh[bsel], (unsigned)__popcll(match));
        active &= ~match;
      }
    }
    __syncthreads();

    // suffix-scan of 4096 bins (512 thr x 8), find cut digit
    unsigned v[8]; unsigned loc = 0;
#pragma unroll
    for (int j = 0; j < 8; ++j) { v[j] = lh[tid*8 + j]; loc += v[j]; }
    lsA[tid] = loc;
    __syncthreads();
    unsigned* s = lsA; unsigned* d = lsB;
    for (int dd = 1; dd < 512; dd <<= 1) {
      unsigned val = s[tid] + ((tid + dd < 512) ? s[tid + dd] : 0u);
      d[tid] = val;
      __syncthreads();
      unsigned* t = s; s = d; d = t;
    }
    unsigned nxt = (tid + 1 < 512) ? s[tid + 1] : 0u;
#pragma unroll
    for (int j = 7; j >= 0; --j) {
      unsigned sfx = nxt + v[j];
      if (sfx >= Rv && nxt < Rv) {
        pfx_s = (pfxv << 12) | (unsigned long long)(unsigned)(tid*8 + j);
        R_s = Rv - nxt;
      }
      nxt = sfx;
    }
    __syncthreads();
  }

  const unsigned long long cut = pfx_s;   // exact rank-512 key (keys distinct)
  for (unsigned i = tid; i < n; i += 512) {
    unsigned long long k = cb[i];
    if (k >= cut) {
      unsigned pos = atomicAdd(&cnt_s, 1u);
      if (pos < 512) sel[pos] = k;
    }
  }
  __syncthreads();

  // bitonic sort 512 desc
  for (int size = 2; size <= 512; size <<= 1) {
    for (int stride = size >> 1; stride > 0; stride >>= 1) {
      int j = tid ^ stride;
      if (j > tid) {
        unsigned long long a = sel[tid], c = sel[j];
        bool up = ((tid & size) == 0);
        if (up ? (a < c) : (a > c)) { sel[tid] = c; sel[j] = a; }
      }
      __syncthreads();
    }
  }
  unsigned long long k = sel[tid];
  unsigned int fbits = (unsigned int)(k >> 18);
  int idx = (IMGPIX-1) - (int)(k & 0x3FFFFull);
  int y = idx >> 9, x = idx & 511;
  float val = fbits ? __uint_as_float(fbits) : -INFINITY;
  int slot = (b << 9) + tid;
  out[12288 + slot]       = val;
  out[8192 + slot*2 + 0]  = (float)x;
  out[8192 + slot*2 + 1]  = (float)y;
  out[14336 + slot]       = (val > NMS_THR) ? 1.0f : 0.0f;
  props[slot*2 + 0] = x;
  props[slot*2 + 1] = y;
}

// ---------------------------------------------------------------------------
// Stage 3+4 (MFMA 32x32x16): 1 proposal/block, 256 thr = 4 waves (r3, best).
// m=2,n=2, acc 64 AGPR + ~64 VGPR -> 128-reg bucket, 4 blocks/CU via 33.6KB LDS.
// ---------------------------------------------------------------------------
#define SA2 264
#define SA1 72
#define ZROW 49

template<int KS, int SA>
__device__ __forceinline__ void conv32(
    const half_t* __restrict__ Wl, const half_t* __restrict__ Xin,
    int mtb, int l31, int lh, f32x16 acc[2][2])
{
#pragma unroll
  for (int mt = 0; mt < 2; ++mt)
#pragma unroll
    for (int nt = 0; nt < 2; ++nt)
#pragma unroll
      for (int r = 0; r < 16; ++r) acc[mt][nt][r] = 0.f;

  for (int tap = 0; tap < 9; ++tap) {
    const int dy = tap/3 - 1, dx = tap%3 - 1;
    int xb[2];
#pragma unroll
    for (int nt = 0; nt < 2; ++nt) {
      int px = nt*32 + l31;
      int y = px/7, x = px - y*7;
      int yy = y + dy, xx = x + dx;
      bool valid = (px < 49) & (yy >= 0) & (yy < 7) & (xx >= 0) & (xx < 7);
      int row = valid ? (yy*7 + xx) : ZROW;
      xb[nt] = row*SA + lh*8;
    }
    const half_t* wb = Wl + ((size_t)(tap*KS)*256 + mtb + l31)*16 + lh*8;
#pragma unroll 4
    for (int ks = 0; ks < KS; ++ks) {
      half8 b0 = *(const half8*)(Xin + xb[0] + ks*16);
      half8 b1 = *(const half8*)(Xin + xb[1] + ks*16);
      half8 a0 = *(const half8*)(wb + (ks*256      )*16);
      half8 a1 = *(const half8*)(wb + (ks*256 + 32 )*16);
      acc[0][0] = __builtin_amdgcn_mfma_f32_32x32x16_f16(a0, b0, acc[0][0], 0,0,0);
      acc[0][1] = __builtin_amdgcn_mfma_f32_32x32x16_f16(a0, b1, acc[0][1], 0,0,0);
      acc[1][0] = __builtin_amdgcn_mfma_f32_32x32x16_f16(a1, b0, acc[1][0], 0,0,0);
      acc[1][1] = __builtin_amdgcn_mfma_f32_32x32x16_f16(a1, b1, acc[1][1], 0,0,0);
    }
  }
}

__device__ __forceinline__ void store32(
    half_t* __restrict__ X2, const float* __restrict__ bias,
    int mtb, int ntb, int l31, int lh, const f32x16& a)
{
  int px = ntb + l31;
  if (px >= 49) return;
  half_t* dst = X2 + px*SA2;
  int oc0 = mtb + 4*lh;
#pragma unroll
  for (int q = 0; q < 4; ++q) {
    int oc = oc0 + 8*q;
    half4 h;
#pragma unroll
    for (int r = 0; r < 4; ++r) {
      float v = a[4*q + r] + bias[oc + r];
      h[r] = (half_t)LRELU_F(v);
    }
    *(half4*)(dst + oc) = h;
  }
}

__global__ __launch_bounds__(256, 4) void head_k(
    const float* __restrict__ fup, const int* __restrict__ props,
    const half_t* __restrict__ W1, const half_t* __restrict__ W2,
    const half_t* __restrict__ W3,
    const float* __restrict__ qb1, const float* __restrict__ qb2,
    const float* __restrict__ qb3,
    const float* __restrict__ qfcw, const float* __restrict__ qfcb,
    float* __restrict__ out)
{
  __shared__ __align__(16) half_t X2[50*SA2];   // 26400 B; rows 0..48, zero row 49
  __shared__ __align__(16) char  U[50*SA1*2];   // X1 (7200 B) / S+P epilogue
  half_t* X1 = (half_t*)U;
  float*  S  = (float*)U;                        // [256] then P [4][256]

  const int p  = blockIdx.x;
  const int b  = p >> 9;
  const int tid = threadIdx.x;
  const int w = tid >> 6, lane = tid & 63;
  const int l31 = lane & 31, lh = lane >> 5;
  const int mtb = w*64;                          // wave = mg, owns 64 oc

  for (int i = tid; i < SA2; i += 256) X2[ZROW*SA2 + i] = (half_t)0.f;
  for (int i = tid; i < SA1; i += 256) X1[ZROW*SA1 + i] = (half_t)0.f;

  // ROI-align (exact reference arithmetic)
  const float step = (float)(10.0/7.0);
  const int cx = props[2*p], cy = props[2*p+1];
  for (int it = tid; it < CUP*49; it += 256) {
    int c = it / 49, bin = it - c*49;
    int iy = bin / 7, ix = bin - iy*7;
    float fy = ((float)cy - 5.0f) + ((float)iy + 0.5f)*step;
    float fx = ((float)cx - 5.0f) + ((float)ix + 0.5f)*step;
    float y0f = floorf(fy), x0f = floorf(fx);
    float wy = fy - y0f,    wx = fx - x0f;
    int y0 = (int)y0f, x0 = (int)x0f;
    int y0i = min(max(y0,   0), 511), y1i = min(max(y0+1, 0), 511);
    int x0i = min(max(x0,   0), 511), x1i = min(max(x0+1, 0), 511);
    const float* f = fup + ((size_t)(b*CUP + c) << 18);
    float v00 = f[(y0i<<9)+x0i], v01 = f[(y0i<<9)+x1i];
    float v10 = f[(y1i<<9)+x0i], v11 = f[(y1i<<9)+x1i];
    float v = v00*(1.f-wy)*(1.f-wx) + v01*(1.f-wy)*wx
            + v10*wy*(1.f-wx)       + v11*wy*wx;
    X1[(iy*7 + ix)*SA1 + c] = (half_t)v;
  }
  __syncthreads();

  f32x16 acc[2][2];

  // conv1: ic=64, KS=4 (X1 -> X2, disjoint buffers: no barrier before store)
  conv32<4, SA1>(W1, X1, mtb, l31, lh, acc);
#pragma unroll
  for (int mt = 0; mt < 2; ++mt)
#pragma unroll
    for (int nt = 0; nt < 2; ++nt)
      store32(X2, qb1, mtb + mt*32, nt*32, l31, lh, acc[mt][nt]);
  __syncthreads();

  // conv2: ic=256, KS=16, in-place
  conv32<16, SA2>(W2, X2, mtb, l31, lh, acc);
  __syncthreads();
#pragma unroll
  for (int mt = 0; mt < 2; ++mt)
#pragma unroll
    for (int nt = 0; nt < 2; ++nt)
      store32(X2, qb2, mtb + mt*32, nt*32, l31, lh, acc[mt][nt]);
  __syncthreads();

  // conv3 + bias + leaky + spatial max over px (S in U, disjoint from X2)
  conv32<16, SA2>(W3, X2, mtb, l31, lh, acc);
#pragma unroll
  for (int mt = 0; mt < 2; ++mt) {
#pragma unroll
    for (int q = 0; q < 4; ++q) {
#pragma unroll
      for (int r = 0; r < 4; ++r) {
        int oc = mtb + mt*32 + 8*q + 4*lh + r;
        float bv = qb3[oc];
        float m = LRELU_F(acc[mt][0][4*q + r] + bv);          // px = l31 < 49
        if (l31 < 17) {
          float v2 = LRELU_F(acc[mt][1][4*q + r] + bv);       // px = 32 + l31
          m = fmaxf(m, v2);
        }
#pragma unroll
        for (int d = 1; d < 32; d <<= 1) m = fmaxf(m, __shfl_xor(m, d));
        if (l31 == 0) S[oc] = m;
      }
    }
  }
  __syncthreads();

  // FC 256 -> 4 (P in U after S; disjoint from S)
  float* P = S + 256;   // [4][256]
  {
    float h = S[tid];
#pragma unroll
    for (int j = 0; j < 4; ++j) P[j*256 + tid] = h * qfcw[j*256 + tid];
  }
  __syncthreads();
  {
    int j = tid >> 6, o = tid & 63;
    float v = P[j*256 + o] + P[j*256 + o + 64]
            + P[j*256 + o + 128] + P[j*256 + o + 192];
#pragma unroll
    for (int d = 1; d < 64; d <<= 1) v += __shfl_xor(v, d);
    if (o == 0) out[p*4 + j] = v + qfcb[j];
  }
}

// ---------------------------------------------------------------------------
extern "C" void kernel_launch(void* const* d_in, const int* in_sizes, int n_in,
                              void* d_out, int out_size, void* d_ws, size_t ws_size,
                              hipStream_t stream)
{
  (void)in_sizes; (void)n_in; (void)out_size; (void)ws_size;
  const float* xhat  = (const float*)d_in[0];
  const float* fdown = (const float*)d_in[1];
  const float* fup   = (const float*)d_in[2];
  const float* pw1   = (const float*)d_in[3];
  const float* pb1   = (const float*)d_in[4];
  const float* pw2   = (const float*)d_in[5];
  const float* pb2   = (const float*)d_in[6];
  const float* pw3   = (const float*)d_in[7];
  const float* pb3   = (const float*)d_in[8];
  const float* pfcw  = (const float*)d_in[9];
  const float* pfcb  = (const float*)d_in[10];
  const float* qw1   = (const float*)d_in[11];
  const float* qb1   = (const float*)d_in[12];
  const float* qw2   = (const float*)d_in[13];
  const float* qb2   = (const float*)d_in[14];
  const float* qw3   = (const float*)d_in[15];
  const float* qb3   = (const float*)d_in[16];
  const float* qfcw  = (const float*)d_in[17];
  const float* qfcb  = (const float*)d_in[18];

  char* ws = (char*)d_ws;
  double*             s32   = (double*)(ws + OFF_S32);
  double*             sum   = (double*)(ws + OFF_SUM);
  unsigned long long* cnt   = (unsigned long long*)(ws + OFF_CNT);
  unsigned int*       ccnt  = (unsigned int*)(ws + OFF_CCNT);
  unsigned long long* bmap  = (unsigned long long*)(ws + OFF_BITMAP);
  unsigned long long* cand  = (unsigned long long*)(ws + OFF_CAND);
  int*                props = (int*)(ws + OFF_PROPS);
  half_t*             Wp1   = (half_t*)(ws + OFF_W1);
  half_t*             Wp2   = (half_t*)(ws + OFF_W2);
  half_t*             Wp3   = (half_t*)(ws + OFF_W3);
  float*              out   = (float*)d_out;

  hipMemsetAsync(ws + ZERO_BASE, 0, ZERO_LEN, stream);

  const int repack_blocks = (36864 + 2*147456 + 255)/256;   // 1296 (half4 quads)
  repatch_k<<<512 + repack_blocks, 256, 0, stream>>>(
      fdown, pw1,pb1, pw2,pb2, pw3,pb3, pfcw,pfcb, s32,
      qw1, qw2, qw3, Wp1, Wp2, Wp3);

  mean_k   <<<4096, 256, 0, stream>>>(xhat, s32, sum, cnt, bmap);
  keyfuse_k<<<256, 512, 0, stream>>>(xhat, bmap, sum, cnt, cand, ccnt);
  select_k <<<BB, 512, 0, stream>>>(cand, ccnt, out, props);
  head_k   <<<NPROP, 256, 0, stream>>>(fup, props, Wp1, Wp2, Wp3,
                                       qb1, qb2, qb3, qfcw, qfcb, out);
}

// Round 5
// 1311.367 us; speedup vs baseline: 1.0631x; 1.0631x over previous
//
#include <hip/hip_runtime.h>
#include <math.h>

typedef _Float16 half_t;
typedef half_t half8 __attribute__((ext_vector_type(8)));
typedef half_t half4 __attribute__((ext_vector_type(4)));
typedef float  f32x16 __attribute__((ext_vector_type(16)));
typedef double dbl2  __attribute__((ext_vector_type(2)));

// Problem constants
#define BB 4
#define HH 512
#define WW 512
#define IMGPIX (HH*WW)        // 262144
#define KSEL 512
#define NPROP (BB*KSEL)       // 2048
#define CUP 64
#define NMS_THR 0.2f

#define CANDCAP (1u<<18)
#define TIECAP  8192

// Workspace layout (bytes)
#define OFF_S32    0                      // double[4096] = 32768
#define OFF_SUM    32768                  // double
#define OFF_CNT    32776                  // ull
#define OFF_CCNT   32784                  // u32[4]
#define OFF_SCNT   32800                  // u32[4]
#define OFF_TCNT   32816                  // u32[4]
#define OFF_CUT    32832                  // u32[4]
#define OFF_HIST0  32896                  // u32[4][4096] = 65536 -> 98432
#define ZERO_BASE  32768
#define ZERO_LEN   65664                  // sum..hist0 inclusive
#define OFF_BITMAP 98432                  // u64[16384] = 131072 -> 229504
#define OFF_CAND   229504                 // u64[4][262144] = 8 MB -> 8618112
#define OFF_SELB   8618112                // u64[4][512] = 16384 -> 8634496
#define OFF_TIEB   8634496                // u64[4][8192] = 262144 -> 8896640
#define OFF_PROPS  8896640                // int[4096] -> 8913024
#define OFF_W1     8913024                // 294912 -> 9207936
#define OFF_W2     9207936                // 1179648 -> 10387584
#define OFF_W3     10387584               // 1179648 -> 11567232 total

#define LRELU_F(x) ((x) > 0.0f ? (x) : 0.1f*(x))

// ---------------------------------------------------------------------------
// Stage 1 (+fused weight repack): blocks 0..511 = patch MLP, rest = repack
// Repack: qw[oc][ic][3][3] f32 -> [tap][ks(ic/16)][oc][16] f16 (coalesced half4)
// ---------------------------------------------------------------------------
__global__ __launch_bounds__(256) void repatch_k(
    const float* __restrict__ fdown,
    const float* __restrict__ pw1, const float* __restrict__ pb1,
    const float* __restrict__ pw2, const float* __restrict__ pb2,
    const float* __restrict__ pw3, const float* __restrict__ pb3,
    const float* __restrict__ pfcw, const float* __restrict__ pfcb,
    double* __restrict__ s32,
    const float* __restrict__ qw1, const float* __restrict__ qw2,
    const float* __restrict__ qw3,
    half_t* __restrict__ W1, half_t* __restrict__ W2, half_t* __restrict__ W3)
{
  if (blockIdx.x >= 512) {
    const int tot1q = (256*64*9)/4*1;          // 36864 quads for W1
    const int tot2q = (256*256*9)/4*1;         // 147456 quads for W2/W3
    int g = (blockIdx.x - 512)*256 + threadIdx.x;
    const float* src; half_t* dst; int IC, KS, q;
    if (g < tot1q)               { src = qw1; dst = W1; IC = 64;  KS = 4;  q = g; }
    else if (g < tot1q + tot2q)  { src = qw2; dst = W2; IC = 256; KS = 16; q = g - tot1q; }
    else if (g < tot1q + 2*tot2q){ src = qw3; dst = W3; IC = 256; KS = 16; q = g - tot1q - tot2q; }
    else return;
    int o4  = q*4;                 // output half index (linear)
    int kin = o4 & 15;
    int t   = o4 >> 4;
    int oc  = t & 255;
    int r   = t >> 8;
    int ks  = r % KS, tap = r / KS;
    half4 h;
#pragma unroll
    for (int j = 0; j < 4; ++j) {
      int ic = ks*16 + kin + j;
      h[j] = (half_t)src[(oc*IC + ic)*9 + tap];
    }
    *(half4*)(dst + o4) = h;
    return;
  }
  __shared__ __align__(16) double xb[8][256];
  const int t = threadIdx.x;
  const int base_px = blockIdx.x * 8;
#pragma unroll
  for (int p = 0; p < 8; ++p) {
    int px = base_px + p;
    int b = px >> 10, rem = px & 1023;
    xb[p][t] = (double)fdown[(size_t)(b*256 + t)*1024 + rem];
  }
  __syncthreads();
  const float* Ws[3] = {pw1, pw2, pw3};
  const float* Bs[3] = {pb1, pb2, pb3};
  for (int L = 0; L < 3; ++L) {
    double acc[8];
    double bias = (double)Bs[L][t];
#pragma unroll
    for (int p = 0; p < 8; ++p) acc[p] = bias;
    const float* wrow = Ws[L] + t*256;
    for (int c = 0; c < 256; c += 2) {
      double w0 = (double)wrow[c], w1 = (double)wrow[c+1];
#pragma unroll
      for (int p = 0; p < 8; ++p) {
        dbl2 xv = *(const dbl2*)&xb[p][c];
        acc[p] += w0 * xv.x;
        acc[p] += w1 * xv.y;
      }
    }
    __syncthreads();
#pragma unroll
    for (int p = 0; p < 8; ++p)
      xb[p][t] = acc[p] > 0.0 ? acc[p] : 0.1*acc[p];
    __syncthreads();
  }
  if (t < 8) {
    double l0 = (double)pfcb[0], l1 = (double)pfcb[1];
    for (int c = 0; c < 256; ++c) {
      double xv = xb[t][c];
      l0 += (double)pfcw[c]       * xv;
      l1 += (double)pfcw[256 + c] * xv;
    }
    double m  = fmax(l0, l1);
    double e0 = exp(l0 - m), e1 = exp(l1 - m);
    s32[base_px + t] = e1 / (e0 + e1);
  }
}

// Bilinear upsample 32->512 (align_corners=False), matches jax.image.resize.
__device__ __forceinline__ double upsample_ps(const double* __restrict__ s32,
                                              int b, int oy, int ox)
{
  double sy = (oy + 0.5)*0.0625 - 0.5;
  double sx = (ox + 0.5)*0.0625 - 0.5;
  double fy = floor(sy), fx = floor(sx);
  double wy = sy - fy,   wx = sx - fx;
  int y0 = (int)fy, x0 = (int)fx;
  int y0i = min(max(y0,   0), 31), y1i = min(max(y0+1, 0), 31);
  int x0i = min(max(x0,   0), 31), x1i = min(max(x0+1, 0), 31);
  const double* s = s32 + b*1024;
  double v00 = s[y0i*32+x0i], v01 = s[y0i*32+x1i];
  double v10 = s[y1i*32+x0i], v11 = s[y1i*32+x1i];
  return v00*(1.0-wy)*(1.0-wx) + v01*(1.0-wy)*wx
       + v10*wy*(1.0-wx)       + v11*wy*wx;
}

// ---------------------------------------------------------------------------
// Stage 2a: global bad-pixel sum/count (f64) + bad bitmap (ballot-packed)
// ---------------------------------------------------------------------------
__global__ __launch_bounds__(256) void mean_k(
    const float* __restrict__ xhat, const double* __restrict__ s32,
    double* __restrict__ sum, unsigned long long* __restrict__ cnt,
    unsigned long long* __restrict__ bitmap)
{
  int id = blockIdx.x*256 + threadIdx.x;
  int b = id >> 18, rem = id & (IMGPIX-1);
  int oy = rem >> 9, ox = rem & 511;
  double ps = upsample_ps(s32, b, oy, ox);
  bool bad = ps < 0.5;
  int lane = threadIdx.x & 63;
  unsigned long long bb = __ballot(bad);
  if (lane == 0) bitmap[id >> 6] = bb;
  double v = bad ? (double)xhat[id] : 0.0;
  int    c = bad ? 1 : 0;
  for (int off = 32; off; off >>= 1) {
    v += __shfl_down(v, off);
    c += __shfl_down(c, off);
  }
  __shared__ double sv[4];
  __shared__ int    sc[4];
  int w = threadIdx.x >> 6;
  if (lane == 0) { sv[w] = v; sc[w] = c; }
  __syncthreads();
  if (threadIdx.x == 0) {
    atomicAdd(sum, sv[0]+sv[1]+sv[2]+sv[3]);
    atomicAdd(cnt, (unsigned long long)(sc[0]+sc[1]+sc[2]+sc[3]));
  }
}

// ---------------------------------------------------------------------------
// Stage 2b: belief map + 7x7 NMS -> compact candidate append (ballot-agg)
//           + 4096-bin bucket histogram (top 12 bits of 50-bit key = key>>38).
// Filler rule: row-0 pixels always appended -> >= 512 keys per image, and
// fillers rank below any appended candidate unless values collide (handled
// exactly by the sort).
// ---------------------------------------------------------------------------
__global__ __launch_bounds__(512) void keyfuse_k(
    const float* __restrict__ xhat, const unsigned long long* __restrict__ bitmap,
    const double* __restrict__ sum, const unsigned long long* __restrict__ cnt,
    unsigned long long* __restrict__ candbuf, unsigned int* __restrict__ ccnt,
    unsigned int* __restrict__ hist0)
{
  __shared__ float rowm[14][512];
  __shared__ float bmv[8][512];
  __shared__ float rt[512];
  __shared__ unsigned int lh[4096];
  const int tid = threadIdx.x;
  const int img = blockIdx.x >> 6;
  const int rb  = (blockIdx.x & 63) * 8;
  for (int i = tid; i < 4096; i += 512) lh[i] = 0;

  unsigned long long n = *cnt; if (n < 1) n = 1;
  const float mean = (float)(*sum / (double)n);
  const int ibase = img * IMGPIX;

  for (int r = 0; r < 14; ++r) {
    int y = rb - 3 + r;
    float v = -INFINITY;
    if (y >= 0 && y < 512) {
      int id = ibase + (y << 9) + tid;
      bool bad = (bitmap[id >> 6] >> (id & 63)) & 1ull;
      v = bad ? mean : xhat[id];
    }
    int cr = y - rb;
    if (cr >= 0 && cr < 8) bmv[cr][tid] = v;
    rt[tid] = v;
    __syncthreads();
    int lo = max(tid-3, 0), hi = min(tid+3, 511);
    float m = rt[lo];
    for (int xx = lo+1; xx <= hi; ++xx) m = fmaxf(m, rt[xx]);
    rowm[r][tid] = m;
    __syncthreads();
  }

  const int lane = tid & 63;
  unsigned long long* cb = candbuf + ((size_t)img << 18);
  for (int yy = 0; yy < 8; ++yy) {
    float mp = rowm[yy][tid];
#pragma unroll
    for (int d = 1; d < 7; ++d) mp = fmaxf(mp, rowm[yy + d][tid]);
    float v = bmv[yy][tid];
    bool cand = (v == mp) && (v > NMS_THR);
    int rem = ((rb + yy) << 9) + tid;
    unsigned int inv = (unsigned int)((IMGPIX-1) - rem);
    unsigned long long key = cand
        ? ((((unsigned long long)__float_as_uint(v)) << 18) | inv)
        : (unsigned long long)inv;
    bool keep = cand | (rem < 512);
    // compact append (ballot-aggregated)
    unsigned long long m = __ballot(keep);
    int c = __popcll(m);
    if (c) {
      int leader = __ffsll((long long)m) - 1;
      unsigned base = 0;
      if (lane == leader) base = atomicAdd(&ccnt[img], (unsigned)c);
      base = __shfl(base, leader);
      if (keep) {
        unsigned rk = (unsigned)__popcll(m & ((1ull << lane) - 1ull));
        cb[base + rk] = key;
      }
    }
    // bucket histogram over APPENDED keys only (ballot-dedup)
    int bin = (int)(key >> 38);
    unsigned long long active = m;
    while (active) {
      int src = __ffsll((long long)active) - 1;
      int bsel = __shfl(bin, src);
      unsigned long long match = __ballot(keep && bin == bsel) & active;
      if (lane == src) atomicAdd(&lh[bsel], (unsigned int)__popcll(match));
      active &= ~match;
    }
  }
  __syncthreads();
  for (int i = tid; i < 4096; i += 512)
    if (lh[i]) atomicAdd(&hist0[img*4096 + i], lh[i]);
}

// Suffix-scan 4096-bin histogram, find bucket containing rank-512 -> cutinfo
__global__ __launch_bounds__(512) void scan0_k(
    const unsigned int* __restrict__ hist0, unsigned int* __restrict__ cutinfo)
{
  __shared__ unsigned int lsA[512], lsB[512];
  const int b = blockIdx.x, tid = threadIdx.x;
  const unsigned int* h = hist0 + b*4096;
  unsigned int v[8]; unsigned int loc = 0;
#pragma unroll
  for (int j = 0; j < 8; ++j) { v[j] = h[tid*8 + j]; loc += v[j]; }
  lsA[tid] = loc;
  __syncthreads();
  unsigned int* s = lsA; unsigned int* d = lsB;
  for (int dd = 1; dd < 512; dd <<= 1) {
    unsigned int val = s[tid] + ((tid + dd < 512) ? s[tid + dd] : 0u);
    d[tid] = val;
    __syncthreads();
    unsigned int* t = s; s = d; d = t;
  }
  unsigned int nxt = (tid + 1 < 512) ? s[tid + 1] : 0u;
#pragma unroll
  for (int j = 7; j >= 0; --j) {
    unsigned int sfx = nxt + v[j];
    if (sfx >= (unsigned)KSEL && nxt < (unsigned)KSEL)
      cutinfo[b] = (unsigned)(tid*8 + j);
    nxt = sfx;
  }
}

// Parallel gather: bucket > cut -> selbuf (A<=511); bucket == cut -> tiebuf.
__global__ __launch_bounds__(512) void gather_k(
    const unsigned long long* __restrict__ candbuf,
    const unsigned int* __restrict__ ccnt, const unsigned int* __restrict__ cutinfo,
    unsigned long long* __restrict__ selbuf, unsigned int* __restrict__ scnt,
    unsigned long long* __restrict__ tiebuf, unsigned int* __restrict__ tcnt)
{
  const int img = blockIdx.x >> 7;            // 128 blocks per image
  unsigned int n = ccnt[img]; if (n > CANDCAP) n = CANDCAP;
  const unsigned int cut = cutinfo[img];
  const unsigned long long* cb = candbuf + ((size_t)img << 18);
  for (unsigned i = (blockIdx.x & 127)*512 + threadIdx.x; i < n; i += 128*512) {
    unsigned long long k = cb[i];
    unsigned bin = (unsigned)(k >> 38);
    if (bin > cut) {
      unsigned pos = atomicAdd(&scnt[img], 1u);
      selbuf[img*512 + pos] = k;               // pos < 512 by cut construction
    } else if (bin == cut) {
      unsigned pos = atomicAdd(&tcnt[img], 1u);
      if (pos < TIECAP) tiebuf[img*TIECAP + pos] = k;
    }
  }
}

// Write the 512 sorted outputs from a desc-sorted LDS array of u64 keys
__device__ __forceinline__ void write_out(
    unsigned long long k, int b, int tid,
    float* __restrict__ out, int* __restrict__ props)
{
  unsigned int fbits = (unsigned int)(k >> 18);
  int idx = (IMGPIX-1) - (int)(k & 0x3FFFFull);
  int y = idx >> 9, x = idx & 511;
  float val = fbits ? __uint_as_float(fbits) : -INFINITY;
  int slot = (b << 9) + tid;
  out[12288 + slot]       = val;
  out[8192 + slot*2 + 0]  = (float)x;
  out[8192 + slot*2 + 1]  = (float)y;
  out[14336 + slot]       = (val > NMS_THR) ? 1.0f : 0.0f;
  props[slot*2 + 0] = x;
  props[slot*2 + 1] = y;
}

// ---------------------------------------------------------------------------
// Finish: fast path = bitonic-8192 sort of {selbuf ∪ tiebuf}, take top 512.
// Fallback (A+T > 8192, pathological): r4's proven 4-pass in-LDS radix over
// the full candidate list.
// ---------------------------------------------------------------------------
__global__ __launch_bounds__(512) void finish_k(
    const unsigned long long* __restrict__ candbuf,
    const unsigned int* __restrict__ ccnt,
    const unsigned long long* __restrict__ selbuf, const unsigned int* __restrict__ scnt,
    const unsigned long long* __restrict__ tiebuf, const unsigned int* __restrict__ tcnt,
    float* __restrict__ out, int* __restrict__ props)
{
  __shared__ __align__(16) unsigned long long s8[8192];   // 64 KB, aliased below
  __shared__ unsigned long long pfx_s;
  __shared__ unsigned int R_s, cnt_s;

  const int b = blockIdx.x, tid = threadIdx.x;
  const int lane = tid & 63;
  const unsigned int A = scnt[b];
  const unsigned int T = tcnt[b];

  if (A + T <= (unsigned)TIECAP) {
    // ---- fast path: sort A+T keys (pad 0), take top 512
    for (int i = tid; i < TIECAP; i += 512) {
      unsigned long long k = 0ull;
      if ((unsigned)i < A) k = selbuf[b*512 + i];
      else if ((unsigned)i < A + T) k = tiebuf[b*TIECAP + (i - (int)A)];
      s8[i] = k;
    }
    __syncthreads();
    for (int k = 2; k <= TIECAP; k <<= 1) {
      for (int j = k >> 1; j > 0; j >>= 1) {
        for (int i = tid; i < TIECAP; i += 512) {
          int ixj = i ^ j;
          if (ixj > i) {
            unsigned long long a = s8[i], c = s8[ixj];
            bool up = ((i & k) == 0);
            if (up ? (a < c) : (a > c)) { s8[i] = c; s8[ixj] = a; }
          }
        }
        __syncthreads();
      }
    }
    write_out(s8[tid], b, tid, out, props);
    return;
  }

  // ---- fallback: r4 select_k (proven) over full candidate list
  unsigned int* lh  = (unsigned int*)s8;          // 4096
  unsigned int* lsA = lh + 4096;                  // 512
  unsigned int* lsB = lsA + 512;                  // 512
  unsigned long long* sel = (unsigned long long*)(lsB + 512);  // 512 u64
  const unsigned long long* cb = candbuf + ((size_t)b << 18);
  unsigned int n = ccnt[b]; if (n > CANDCAP) n = CANDCAP;

  if (tid == 0) { pfx_s = 0ull; R_s = (unsigned)KSEL; cnt_s = 0u; }
  __syncthreads();

  for (int pass = 0; pass < 4; ++pass) {
    const int shift = 36 - 12*pass;
    const unsigned long long pfxv = pfx_s;
    const unsigned int Rv = R_s;
    for (int i = tid; i < 4096; i += 512) lh[i] = 0;
    __syncthreads();
    for (unsigned i0 = 0; i0 < n; i0 += 512) {
      unsigned i = i0 + tid;
      unsigned long long k = (i < n) ? cb[i] : 0ull;
      bool pred = (i < n) && (pass == 0 || (k >> (shift + 12)) == pfxv);
      int bin = (int)((unsigned)(k >> shift) & 4095u);
      unsigned long long active = __ballot(pred);
      while (active) {
        int src = __ffsll((long long)active) - 1;
        int bsel = __shfl(bin, src);
        unsigned long long match = __ballot(bin == bsel) & active;
        if (lane == src) atomicAdd(&lh[bsel], (unsigned)__popcll(match));
        active &= ~match;
      }
    }
    __syncthreads();
    unsigned v[8]; unsigned loc = 0;
#pragma unroll
    for (int j = 0; j < 8; ++j) { v[j] = lh[tid*8 + j]; loc += v[j]; }
    lsA[tid] = loc;
    __syncthreads();
    unsigned* s = lsA; unsigned* d = lsB;
    for (int dd = 1; dd < 512; dd <<= 1) {
      unsigned val = s[tid] + ((tid + dd < 512) ? s[tid + dd] : 0u);
      d[tid] = val;
      __syncthreads();
      unsigned* t = s; s = d; d = t;
    }
    unsigned nxt = (tid + 1 < 512) ? s[tid + 1] : 0u;
#pragma unroll
    for (int j = 7; j >= 0; --j) {
      unsigned sfx = nxt + v[j];
      if (sfx >= Rv && nxt < Rv) {
        pfx_s = (pfxv << 12) | (unsigned long long)(unsigned)(tid*8 + j);
        R_s = Rv - nxt;
      }
      nxt = sfx;
    }
    __syncthreads();
  }

  const unsigned long long cut = pfx_s;
  for (unsigned i = tid; i < n; i += 512) {
    unsigned long long k = cb[i];
    if (k >= cut) {
      unsigned pos = atomicAdd(&cnt_s, 1u);
      if (pos < 512) sel[pos] = k;
    }
  }
  __syncthreads();
  for (int k = 2; k <= 512; k <<= 1) {
    for (int stride = k >> 1; stride > 0; stride >>= 1) {
      int j = tid ^ stride;
      if (j > tid) {
        unsigned long long a = sel[tid], c = sel[j];
        bool up = ((tid & k) == 0);
        if (up ? (a < c) : (a > c)) { sel[tid] = c; sel[j] = a; }
      }
      __syncthreads();
    }
  }
  write_out(sel[tid], b, tid, out, props);
}

// ---------------------------------------------------------------------------
// Stage 3+4 (MFMA 32x32x16): 1 proposal/block, 256 thr = 4 waves (r3, best).
// m=2,n=2, acc 64 AGPR + ~64 VGPR -> 128-reg bucket, 4 blocks/CU via 33.6KB LDS.
// ---------------------------------------------------------------------------
#define SA2 264
#define SA1 72
#define ZROW 49

template<int KS, int SA>
__device__ __forceinline__ void conv32(
    const half_t* __restrict__ Wl, const half_t* __restrict__ Xin,
    int mtb, int l31, int lh, f32x16 acc[2][2])
{
#pragma unroll
  for (int mt = 0; mt < 2; ++mt)
#pragma unroll
    for (int nt = 0; nt < 2; ++nt)
#pragma unroll
      for (int r = 0; r < 16; ++r) acc[mt][nt][r] = 0.f;

  for (int tap = 0; tap < 9; ++tap) {
    const int dy = tap/3 - 1, dx = tap%3 - 1;
    int xb[2];
#pragma unroll
    for (int nt = 0; nt < 2; ++nt) {
      int px = nt*32 + l31;
      int y = px/7, x = px - y*7;
      int yy = y + dy, xx = x + dx;
      bool valid = (px < 49) & (yy >= 0) & (yy < 7) & (xx >= 0) & (xx < 7);
      int row = valid ? (yy*7 + xx) : ZROW;
      xb[nt] = row*SA + lh*8;
    }
    const half_t* wb = Wl + ((size_t)(tap*KS)*256 + mtb + l31)*16 + lh*8;
#pragma unroll 4
    for (int ks = 0; ks < KS; ++ks) {
      half8 b0 = *(const half8*)(Xin + xb[0] + ks*16);
      half8 b1 = *(const half8*)(Xin + xb[1] + ks*16);
      half8 a0 = *(const half8*)(wb + (ks*256      )*16);
      half8 a1 = *(const half8*)(wb + (ks*256 + 32 )*16);
      acc[0][0] = __builtin_amdgcn_mfma_f32_32x32x16_f16(a0, b0, acc[0][0], 0,0,0);
      acc[0][1] = __builtin_amdgcn_mfma_f32_32x32x16_f16(a0, b1, acc[0][1], 0,0,0);
      acc[1][0] = __builtin_amdgcn_mfma_f32_32x32x16_f16(a1, b0, acc[1][0], 0,0,0);
      acc[1][1] = __builtin_amdgcn_mfma_f32_32x32x16_f16(a1, b1, acc[1][1], 0,0,0);
    }
  }
}

__device__ __forceinline__ void store32(
    half_t* __restrict__ X2, const float* __restrict__ bias,
    int mtb, int ntb, int l31, int lh, const f32x16& a)
{
  int px = ntb + l31;
  if (px >= 49) return;
  half_t* dst = X2 + px*SA2;
  int oc0 = mtb + 4*lh;
#pragma unroll
  for (int q = 0; q < 4; ++q) {
    int oc = oc0 + 8*q;
    half4 h;
#pragma unroll
    for (int r = 0; r < 4; ++r) {
      float v = a[4*q + r] + bias[oc + r];
      h[r] = (half_t)LRELU_F(v);
    }
    *(half4*)(dst + oc) = h;
  }
}

__global__ __launch_bounds__(256, 4) void head_k(
    const float* __restrict__ fup, const int* __restrict__ props,
    const half_t* __restrict__ W1, const half_t* __restrict__ W2,
    const half_t* __restrict__ W3,
    const float* __restrict__ qb1, const float* __restrict__ qb2,
    const float* __restrict__ qb3,
    const float* __restrict__ qfcw, const float* __restrict__ qfcb,
    float* __restrict__ out)
{
  __shared__ __align__(16) half_t X2[50*SA2];   // 26400 B; rows 0..48, zero row 49
  __shared__ __align__(16) char  U[50*SA1*2];   // X1 (7200 B) / S+P epilogue
  half_t* X1 = (half_t*)U;
  float*  S  = (float*)U;                        // [256] then P [4][256]

  const int p  = blockIdx.x;
  const int b  = p >> 9;
  const int tid = threadIdx.x;
  const int w = tid >> 6, lane = tid & 63;
  const int l31 = lane & 31, lh = lane >> 5;
  const int mtb = w*64;                          // wave = mg, owns 64 oc

  for (int i = tid; i < SA2; i += 256) X2[ZROW*SA2 + i] = (half_t)0.f;
  for (int i = tid; i < SA1; i += 256) X1[ZROW*SA1 + i] = (half_t)0.f;

  // ROI-align (exact reference arithmetic)
  const float step = (float)(10.0/7.0);
  const int cx = props[2*p], cy = props[2*p+1];
  for (int it = tid; it < CUP*49; it += 256) {
    int c = it / 49, bin = it - c*49;
    int iy = bin / 7, ix = bin - iy*7;
    float fy = ((float)cy - 5.0f) + ((float)iy + 0.5f)*step;
    float fx = ((float)cx - 5.0f) + ((float)ix + 0.5f)*step;
    float y0f = floorf(fy), x0f = floorf(fx);
    float wy = fy - y0f,    wx = fx - x0f;
    int y0 = (int)y0f, x0 = (int)x0f;
    int y0i = min(max(y0,   0), 511), y1i = min(max(y0+1, 0), 511);
    int x0i = min(max(x0,   0), 511), x1i = min(max(x0+1, 0), 511);
    const float* f = fup + ((size_t)(b*CUP + c) << 18);
    float v00 = f[(y0i<<9)+x0i], v01 = f[(y0i<<9)+x1i];
    float v10 = f[(y1i<<9)+x0i], v11 = f[(y1i<<9)+x1i];
    float v = v00*(1.f-wy)*(1.f-wx) + v01*(1.f-wy)*wx
            + v10*wy*(1.f-wx)       + v11*wy*wx;
    X1[(iy*7 + ix)*SA1 + c] = (half_t)v;
  }
  __syncthreads();

  f32x16 acc[2][2];

  // conv1: ic=64, KS=4 (X1 -> X2, disjoint buffers: no barrier before store)
  conv32<4, SA1>(W1, X1, mtb, l31, lh, acc);
#pragma unroll
  for (int mt = 0; mt < 2; ++mt)
#pragma unroll
    for (int nt = 0; nt < 2; ++nt)
      store32(X2, qb1, mtb + mt*32, nt*32, l31, lh, acc[mt][nt]);
  __syncthreads();

  // conv2: ic=256, KS=16, in-place
  conv32<16, SA2>(W2, X2, mtb, l31, lh, acc);
  __syncthreads();
#pragma unroll
  for (int mt = 0; mt < 2; ++mt)
#pragma unroll
    for (int nt = 0; nt < 2; ++nt)
      store32(X2, qb2, mtb + mt*32, nt*32, l31, lh, acc[mt][nt]);
  __syncthreads();

  // conv3 + bias + leaky + spatial max over px (S in U, disjoint from X2)
  conv32<16, SA2>(W3, X2, mtb, l31, lh, acc);
#pragma unroll
  for (int mt = 0; mt < 2; ++mt) {
#pragma unroll
    for (int q = 0; q < 4; ++q) {
#pragma unroll
      for (int r = 0; r < 4; ++r) {
        int oc = mtb + mt*32 + 8*q + 4*lh + r;
        float bv = qb3[oc];
        float m = LRELU_F(acc[mt][0][4*q + r] + bv);          // px = l31 < 49
        if (l31 < 17) {
          float v2 = LRELU_F(acc[mt][1][4*q + r] + bv);       // px = 32 + l31
          m = fmaxf(m, v2);
        }
#pragma unroll
        for (int d = 1; d < 32; d <<= 1) m = fmaxf(m, __shfl_xor(m, d));
        if (l31 == 0) S[oc] = m;
      }
    }
  }
  __syncthreads();

  // FC 256 -> 4 (P in U after S; disjoint from S)
  float* P = S + 256;   // [4][256]
  {
    float h = S[tid];
#pragma unroll
    for (int j = 0; j < 4; ++j) P[j*256 + tid] = h * qfcw[j*256 + tid];
  }
  __syncthreads();
  {
    int j = tid >> 6, o = tid & 63;
    float v = P[j*256 + o] + P[j*256 + o + 64]
            + P[j*256 + o + 128] + P[j*256 + o + 192];
#pragma unroll
    for (int d = 1; d < 64; d <<= 1) v += __shfl_xor(v, d);
    if (o == 0) out[p*4 + j] = v + qfcb[j];
  }
}

// ---------------------------------------------------------------------------
extern "C" void kernel_launch(void* const* d_in, const int* in_sizes, int n_in,
                              void* d_out, int out_size, void* d_ws, size_t ws_size,
                              hipStream_t stream)
{
  (void)in_sizes; (void)n_in; (void)out_size; (void)ws_size;
  const float* xhat  = (const float*)d_in[0];
  const float* fdown = (const float*)d_in[1];
  const float* fup   = (const float*)d_in[2];
  const float* pw1   = (const float*)d_in[3];
  const float* pb1   = (const float*)d_in[4];
  const float* pw2   = (const float*)d_in[5];
  const float* pb2   = (const float*)d_in[6];
  const float* pw3   = (const float*)d_in[7];
  const float* pb3   = (const float*)d_in[8];
  const float* pfcw  = (const float*)d_in[9];
  const float* pfcb  = (const float*)d_in[10];
  const float* qw1   = (const float*)d_in[11];
  const float* qb1   = (const float*)d_in[12];
  const float* qw2   = (const float*)d_in[13];
  const float* qb2   = (const float*)d_in[14];
  const float* qw3   = (const float*)d_in[15];
  const float* qb3   = (const float*)d_in[16];
  const float* qfcw  = (const float*)d_in[17];
  const float* qfcb  = (const float*)d_in[18];

  char* ws = (char*)d_ws;
  double*             s32   = (double*)(ws + OFF_S32);
  double*             sum   = (double*)(ws + OFF_SUM);
  unsigned long long* cnt   = (unsigned long long*)(ws + OFF_CNT);
  unsigned int*       ccnt  = (unsigned int*)(ws + OFF_CCNT);
  unsigned int*       scnt  = (unsigned int*)(ws + OFF_SCNT);
  unsigned int*       tcnt  = (unsigned int*)(ws + OFF_TCNT);
  unsigned int*       cut   = (unsigned int*)(ws + OFF_CUT);
  unsigned int*       hist0 = (unsigned int*)(ws + OFF_HIST0);
  unsigned long long* bmap  = (unsigned long long*)(ws + OFF_BITMAP);
  unsigned long long* cand  = (unsigned long long*)(ws + OFF_CAND);
  unsigned long long* selb  = (unsigned long long*)(ws + OFF_SELB);
  unsigned long long* tieb  = (unsigned long long*)(ws + OFF_TIEB);
  int*                props = (int*)(ws + OFF_PROPS);
  half_t*             Wp1   = (half_t*)(ws + OFF_W1);
  half_t*             Wp2   = (half_t*)(ws + OFF_W2);
  half_t*             Wp3   = (half_t*)(ws + OFF_W3);
  float*              out   = (float*)d_out;

  hipMemsetAsync(ws + ZERO_BASE, 0, ZERO_LEN, stream);

  const int repack_blocks = (36864 + 2*147456 + 255)/256;   // 1296
  repatch_k<<<512 + repack_blocks, 256, 0, stream>>>(
      fdown, pw1,pb1, pw2,pb2, pw3,pb3, pfcw,pfcb, s32,
      qw1, qw2, qw3, Wp1, Wp2, Wp3);

  mean_k   <<<4096, 256, 0, stream>>>(xhat, s32, sum, cnt, bmap);
  keyfuse_k<<<256, 512, 0, stream>>>(xhat, bmap, sum, cnt, cand, ccnt, hist0);
  scan0_k  <<<BB, 512, 0, stream>>>(hist0, cut);
  gather_k <<<BB*128, 512, 0, stream>>>(cand, ccnt, cut, selb, scnt, tieb, tcnt);
  finish_k <<<BB, 512, 0, stream>>>(cand, ccnt, selb, scnt, tieb, tcnt, out, props);
  head_k   <<<NPROP, 256, 0, stream>>>(fup, props, Wp1, Wp2, Wp3,
                                       qb1, qb2, qb3, qfcw, qfcb, out);
}